// Round 1
// baseline (65.861 us; speedup 1.0000x reference)
//
#include <hip/hip_runtime.h>

// Keypoint decoder collapses analytically:
//   scores has C=1 (dc_w is (1,2,5,5) -> 1 output channel), and the final op
//   is softmax over axis=1 (size 1) => output is exactly 1.0f everywhere.
// So kernel_launch only needs to fill d_out (8*1*320*320 fp32) with 1.0f.

__global__ void __launch_bounds__(256) fill_ones_kernel(float4* __restrict__ out4,
                                                        int n4,
                                                        float* __restrict__ out_tail,
                                                        int tail_start,
                                                        int n_total) {
    int i = blockIdx.x * blockDim.x + threadIdx.x;
    if (i < n4) {
        out4[i] = make_float4(1.0f, 1.0f, 1.0f, 1.0f);
    }
    // Tail (out_size not divisible by 4) — handled by the first few threads.
    int t = tail_start + i;
    if (i < 4 && t < n_total) {
        out_tail[t] = 1.0f;
    }
}

extern "C" void kernel_launch(void* const* d_in, const int* in_sizes, int n_in,
                              void* d_out, int out_size, void* d_ws, size_t ws_size,
                              hipStream_t stream) {
    (void)d_in; (void)in_sizes; (void)n_in; (void)d_ws; (void)ws_size;

    float* out = (float*)d_out;
    int n = out_size;            // expected 8*1*320*320 = 819200
    int n4 = n >> 2;             // float4 chunks
    int tail_start = n4 << 2;

    int threads = 256;
    int blocks = (n4 + threads - 1) / threads;
    if (blocks < 1) blocks = 1;

    fill_ones_kernel<<<blocks, threads, 0, stream>>>(
        (float4*)out, n4, out, tail_start, n);
}